// Round 1
// baseline (2118.590 us; speedup 1.0000x reference)
//
#include <hip/hip_runtime.h>

// ---------------------------------------------------------------------------
// Agent forward pass on MI355X.
//   prep kernels (weight->bf16, pre-gates, convs, fc)  [stream-serial]
//   one persistent flag-pipelined kernel:
//     blocks 0..127 : mem LSTM layers 0..3 (32 blocks/layer, 16 hidden units each)
//     blocks 128..143: enc LSTM (16 blocks, 16 units each)
//     block 144      : emb (lang_e) + hidden concat
//     block 145      : actor/critic heads + log_softmax
//   Per-(layer,t) device-scope flags; layers pipeline with skew 1.
//   Recurrent weights held in VGPRs as MFMA B-fragments (persistent-RNN style).
// ---------------------------------------------------------------------------

typedef __bf16 bf16;
typedef __bf16 bf16x8 __attribute__((ext_vector_type(8)));
typedef float f32x4v __attribute__((ext_vector_type(4)));
typedef float f32x16v __attribute__((ext_vector_type(16)));

#define SCOPE_AGENT __HIP_MEMORY_SCOPE_AGENT
#define HM_ELEMS (65 * 32 * 512)   // one mem-layer h array: [65 slots][32][512]

__device__ __forceinline__ float sigf_(float x) {
  x = fminf(fmaxf(x, -30.f), 30.f);
  return 1.f / (1.f + __expf(-x));
}
__device__ __forceinline__ float tanhf_(float x) {
  x = fminf(fmaxf(x, -15.f), 15.f);
  float e = __expf(2.f * x);
  return (e - 1.f) / (e + 1.f);
}
__device__ __forceinline__ void wait_ge(int* f, int need) {
  while (__hip_atomic_load(f, __ATOMIC_RELAXED, SCOPE_AGENT) < need)
    __builtin_amdgcn_s_sleep(1);
}

// stage 32 rows x KLEN bf16 (contiguous rows) into swizzled LDS A-buffer at column koff.
// maskrow != null: zero row m when maskrow[m] != 0 (done flag -> reset h).
template<int KS_PAD, int KLEN>
__device__ __forceinline__ void stage32(bf16* __restrict__ dst, const bf16* __restrict__ src,
                                        int koff, const float* __restrict__ maskrow, int tid) {
  constexpr int VPR = KLEN / 8;
  constexpr int TOT = 32 * VPR;
  for (int i = tid; i < TOT; i += 256) {
    int m = i / VPR;
    int kb = (i - m * VPR) * 8;
    uint4 v = *(const uint4*)(src + m * KLEN + kb);
    if (maskrow != nullptr && maskrow[m] != 0.0f) { v.x = 0u; v.y = 0u; v.z = 0u; v.w = 0u; }
    int kd = koff + kb;
    *(uint4*)(dst + m * KS_PAD + (kd ^ ((m & 15) * 8))) = v;
  }
}

// ---------------------------------------------------------------------------
// Generic LSTM scan block. Owns 16 hidden units (= 64 gate cols, i|f|g|o x 16).
// 4 waves split K 4-ways; each wave: 2 N-tiles (32 cols) of 32x32x16 MFMA.
// Gates reduced via LDS partials; c kept in LDS fp32; h written bf16 to global.
// ---------------------------------------------------------------------------
template<int KS_PAD, int KTOT, int NKS, bool GUARD, int HDIM, bool PRE, int XLEN>
__device__ void scan_body(const bf16* __restrict__ Wrows, const float* __restrict__ biasf,
    const bf16* __restrict__ xbase, const bf16* __restrict__ hbase, bf16* __restrict__ hout,
    const float* __restrict__ cinit, const float* __restrict__ done,
    int* flag_own, int need_own, int* flag_x, int need_x, int* flag_post,
    int u0, int tid, char* smem)
{
  constexpr int KW = KTOT * 16;                   // actual weight row length
  bf16* Abuf = (bf16*)smem;                       // [32][KS_PAD] swizzled
  float* partial = (float*)(smem + 32 * KS_PAD * 2); // [4][64][36]
  float* cl = partial + 4 * 64 * 36;              // [32][16] cell state
  const int lane = tid & 63, wv = tid >> 6;
  const int hsel = lane >> 5, ln31 = lane & 31;
  const int ks0 = wv * NKS;

  // ---- preload this wave's B-fragments of W into registers (time-invariant) ----
  bf16x8 Wreg[2][NKS];
#pragma unroll
  for (int nt = 0; nt < 2; ++nt) {
    int n = nt * 32 + ln31;                        // local col 0..63
    int row = (n >> 4) * HDIM + u0 + (n & 15);     // global gate col
#pragma unroll
    for (int ks = 0; ks < NKS; ++ks) {
      bf16x8 w8 = {};
      if (!GUARD || (ks0 + ks) < KTOT)
        w8 = *(const bf16x8*)(Wrows + row * KW + (ks0 + ks) * 16 + hsel * 8);
      Wreg[nt][ks] = w8;
    }
  }
  for (int i = tid; i < 512; i += 256)
    cl[i] = cinit[(i >> 4) * HDIM + u0 + (i & 15)];

  for (int t = 0; t < 64; ++t) {
    if (tid == 0) {
      if (t > 0) wait_ge(flag_own + (t - 1), need_own);
      if (need_x > 0) wait_ge(flag_x + t, need_x);
      __builtin_amdgcn_fence(__ATOMIC_ACQUIRE, "agent");
    }
    __syncthreads();
    if constexpr (XLEN > 0)
      stage32<KS_PAD, (XLEN > 0 ? XLEN : 8)>(Abuf, xbase + t * 32 * XLEN, 0, nullptr, tid);
    stage32<KS_PAD, HDIM>(Abuf, hbase + t * 32 * HDIM, XLEN, done + t * 32, tid);
    __syncthreads();

    f32x16v acc0 = {}, acc1 = {};
#pragma unroll
    for (int ks = 0; ks < NKS; ++ks) {
      if (!GUARD || (ks0 + ks) < KTOT) {
        int k = (ks0 + ks) * 16 + hsel * 8;
        bf16x8 a = *(const bf16x8*)(Abuf + ln31 * KS_PAD + (k ^ ((ln31 & 15) * 8)));
        acc0 = __builtin_amdgcn_mfma_f32_32x32x16_bf16(a, Wreg[0][ks], acc0, 0, 0, 0);
        acc1 = __builtin_amdgcn_mfma_f32_32x32x16_bf16(a, Wreg[1][ks], acc1, 0, 0, 0);
      }
    }
    // partials: [wave][n][m(pad36)] ; C/D: n=lane&31, m=(reg&3)+8*(reg>>2)+4*(lane>>5)
#pragma unroll
    for (int nt = 0; nt < 2; ++nt) {
      int n = nt * 32 + ln31;
      const f32x16v& A = nt ? acc1 : acc0;
#pragma unroll
      for (int q = 0; q < 4; ++q) {
        f32x4v v; v[0] = A[4*q+0]; v[1] = A[4*q+1]; v[2] = A[4*q+2]; v[3] = A[4*q+3];
        *(f32x4v*)(partial + (wv * 64 + n) * 36 + 8 * q + 4 * hsel) = v;
      }
    }
    __syncthreads();
    for (int e = tid; e < 512; e += 256) {
      int m = e >> 4, u = e & 15;
      float gg[4];
#pragma unroll
      for (int g = 0; g < 4; ++g) {
        int n = g * 16 + u;
        float s = partial[n * 36 + m] + partial[(64 + n) * 36 + m]
                + partial[(128 + n) * 36 + m] + partial[(192 + n) * 36 + m];
        if (PRE) s += biasf[(t * 32 + m) * (4 * HDIM) + g * HDIM + u0 + u];
        else     s += biasf[g * HDIM + u0 + u];
        gg[g] = s;
      }
      float mask = 1.0f - done[t * 32 + m];
      float cold = cl[e] * mask;
      float cn = sigf_(gg[1]) * cold + sigf_(gg[0]) * tanhf_(gg[2]);
      float hn = sigf_(gg[3]) * tanhf_(cn);
      cl[e] = cn;
      hout[(t + 1) * 32 * HDIM + m * HDIM + u0 + u] = (bf16)hn;
    }
    __syncthreads();
    if (tid == 0) {
      __builtin_amdgcn_fence(__ATOMIC_RELEASE, "agent");
      __hip_atomic_fetch_add(flag_post + t, 1, __ATOMIC_RELAXED, SCOPE_AGENT);
    }
  }
}

// ---- emb block: lang_e[t] = relu(lang_h[t] @ emb_w.T + emb_b) -> hidden[:,256:288]
__device__ void emb_body(const bf16* __restrict__ Wemb, const float* __restrict__ emb_b,
    const bf16* __restrict__ h_enc, bf16* __restrict__ hidden,
    int* fle, int* flb, int tid, char* smem)
{
  bf16* Abuf = (bf16*)smem;
  float* partial = (float*)(smem + 32 * 256 * 2);
  const int lane = tid & 63, wv = tid >> 6;
  const int hsel = lane >> 5, ln31 = lane & 31;
  const int ks0 = wv * 4;
  bf16x8 Wreg[4];
#pragma unroll
  for (int ks = 0; ks < 4; ++ks)
    Wreg[ks] = *(const bf16x8*)(Wemb + ln31 * 256 + (ks0 + ks) * 16 + hsel * 8);
  for (int t = 0; t < 64; ++t) {
    if (tid == 0) { wait_ge(fle + t, 16); __builtin_amdgcn_fence(__ATOMIC_ACQUIRE, "agent"); }
    __syncthreads();
    stage32<256, 256>(Abuf, h_enc + (t + 1) * 32 * 256, 0, nullptr, tid);
    __syncthreads();
    f32x16v acc = {};
#pragma unroll
    for (int ks = 0; ks < 4; ++ks) {
      int k = (ks0 + ks) * 16 + hsel * 8;
      bf16x8 a = *(const bf16x8*)(Abuf + ln31 * 256 + (k ^ ((ln31 & 15) * 8)));
      acc = __builtin_amdgcn_mfma_f32_32x32x16_bf16(a, Wreg[ks], acc, 0, 0, 0);
    }
#pragma unroll
    for (int q = 0; q < 4; ++q) {
      f32x4v v; v[0] = acc[4*q+0]; v[1] = acc[4*q+1]; v[2] = acc[4*q+2]; v[3] = acc[4*q+3];
      *(f32x4v*)(partial + (wv * 32 + ln31) * 36 + 8 * q + 4 * hsel) = v;
    }
    __syncthreads();
    for (int e = tid; e < 1024; e += 256) {
      int m = e >> 5, n = e & 31;
      float s = partial[n * 36 + m] + partial[(32 + n) * 36 + m]
              + partial[(64 + n) * 36 + m] + partial[(96 + n) * 36 + m] + emb_b[n];
      hidden[(t * 32 + m) * 288 + 256 + n] = (bf16)fmaxf(s, 0.f);
    }
    __syncthreads();
    if (tid == 0) {
      __builtin_amdgcn_fence(__ATOMIC_RELEASE, "agent");
      __hip_atomic_fetch_add(flb + t, 1, __ATOMIC_RELAXED, SCOPE_AGENT);
    }
  }
}

// ---- heads block: logits, log_softmax, entropy, value, write output
__device__ void heads_body(const bf16* __restrict__ h3, const float* __restrict__ actor_w,
    const float* __restrict__ actor_b, const float* __restrict__ critic_w,
    const float* __restrict__ critic_b, const int* __restrict__ action,
    float* __restrict__ out, int* fl3, int tid, char* smem)
{
  float* hS = (float*)smem;       // [32][520] padded
  float* lg = hS + 32 * 520;      // [32][8]
  float* vp = lg + 256;           // [32][8]
  const int b = tid >> 3, c = tid & 7;
  for (int t = 0; t < 64; ++t) {
    if (tid == 0) { wait_ge(fl3 + t, 32); __builtin_amdgcn_fence(__ATOMIC_ACQUIRE, "agent"); }
    __syncthreads();
    for (int i = tid; i < 2048; i += 256) {
      int m = i >> 6, kb = (i & 63) * 8;
      bf16x8 v = *(const bf16x8*)(h3 + (t + 1) * 32 * 512 + m * 512 + kb);
#pragma unroll
      for (int j = 0; j < 8; ++j) hS[m * 520 + kb + j] = (float)v[j];
    }
    __syncthreads();
    float acc = actor_b[c];
    float va = 0.f;
#pragma unroll 4
    for (int k = 0; k < 512; k += 4) {
      f32x4v hv = *(const f32x4v*)(hS + b * 520 + k);
      f32x4v wv4 = *(const f32x4v*)(actor_w + c * 512 + k);
      acc += hv[0]*wv4[0] + hv[1]*wv4[1] + hv[2]*wv4[2] + hv[3]*wv4[3];
    }
    for (int k = c * 64; k < c * 64 + 64; k += 4) {
      f32x4v hv = *(const f32x4v*)(hS + b * 520 + k);
      f32x4v wv4 = *(const f32x4v*)(critic_w + k);
      va += hv[0]*wv4[0] + hv[1]*wv4[1] + hv[2]*wv4[2] + hv[3]*wv4[3];
    }
    lg[b * 8 + c] = acc;
    vp[b * 8 + c] = va;
    __syncthreads();
    if (tid < 32) {
      const float* L = lg + tid * 8;
      float mx = L[0];
#pragma unroll
      for (int i = 1; i < 8; ++i) mx = fmaxf(mx, L[i]);
      float s = 0.f;
#pragma unroll
      for (int i = 0; i < 8; ++i) s += __expf(L[i] - mx);
      float lse = mx + __logf(s);
      float ent = 0.f;
#pragma unroll
      for (int i = 0; i < 8; ++i) { float lp = L[i] - lse; ent -= __expf(lp) * lp; }
      int a = action[t * 32 + tid];
      a = a < 0 ? 0 : (a > 7 ? 7 : a);
      float val = critic_b[0];
#pragma unroll
      for (int i = 0; i < 8; ++i) val += vp[tid * 8 + i];
      float* o = out + (t * 32 + tid) * 3;
      o[0] = L[a] - lse; o[1] = ent; o[2] = val;
    }
    __syncthreads();
  }
}

struct PipeP {
  const bf16 *Wenc, *Wm0, *Wm1, *Wm2, *Wm3, *Wemb;
  const float *pre_enc, *bc, *done, *emb_b, *enc_c0, *mem_c0;
  bf16 *hidden, *h_enc, *h_mem;
  const float *actor_w, *actor_b, *critic_w, *critic_b;
  const int *action;
  float *out;
  int *fl;
};

__global__ __launch_bounds__(256, 1) void pipeline_kernel(PipeP P) {
  extern __shared__ char smem[];
  const int bid = blockIdx.x, tid = threadIdx.x;
  int* flm = P.fl;            // [4][64]
  int* fle = P.fl + 256;      // [64]
  int* flb = P.fl + 320;      // [64]
  if (bid < 128) {
    int l = bid >> 5, u0 = (bid & 31) * 16;
    bf16* hown = P.h_mem + l * HM_ELEMS;
    if (l == 0) {
      scan_body<1024, 50, 13, true, 512, false, 288>(P.Wm0, P.bc, P.hidden, hown, hown,
          P.mem_c0, P.done, flm, 32, flb, 1, flm, u0, tid, smem);
    } else {
      const bf16* W = (l == 1) ? P.Wm1 : (l == 2) ? P.Wm2 : P.Wm3;
      scan_body<1024, 64, 16, false, 512, false, 512>(W, P.bc + l * 2048,
          P.h_mem + (l - 1) * HM_ELEMS + 32 * 512, hown, hown,
          P.mem_c0 + l * 32 * 512, P.done,
          flm + l * 64, 32, flm + (l - 1) * 64, 32, flm + l * 64, u0, tid, smem);
    }
  } else if (bid < 144) {
    int u0 = (bid - 128) * 16;
    scan_body<256, 16, 4, false, 256, true, 0>(P.Wenc, P.pre_enc, nullptr, P.h_enc, P.h_enc,
        P.enc_c0, P.done, fle, 16, nullptr, 0, fle, u0, tid, smem);
  } else if (bid == 144) {
    emb_body(P.Wemb, P.emb_b, P.h_enc, P.hidden, fle, flb, tid, smem);
  } else {
    heads_body(P.h_mem + 3 * HM_ELEMS, P.actor_w, P.actor_b, P.critic_w, P.critic_b,
        P.action, P.out, flm + 192, tid, smem);
  }
}

// ---------------------------------------------------------------------------
// prep: weight conversions / concat layouts / initial h slots
// ---------------------------------------------------------------------------
__global__ void prep_kernel(
    const float* __restrict__ enc_Whh, const float* __restrict__ mem_Wih0,
    const float* __restrict__ mem_WihR, const float* __restrict__ mem_Whh,
    const float* __restrict__ emb_w, const float* __restrict__ mem_bih,
    const float* __restrict__ mem_bhh, const float* __restrict__ enc_h0,
    const float* __restrict__ mem_h0, const float* __restrict__ fc_w,
    bf16* __restrict__ Wenc, bf16* __restrict__ Wm0, bf16* __restrict__ Wm123,
    bf16* __restrict__ Wemb, float* __restrict__ bc,
    bf16* __restrict__ h_enc, bf16* __restrict__ h_mem, bf16* __restrict__ fcw_bf)
{
  int i = blockIdx.x * 256 + threadIdx.x;
  if (i < 262144) { Wenc[i] = (bf16)enc_Whh[i]; return; }
  i -= 262144;
  if (i < 1638400) {    // Wm0: [2048][288 Wih0 | 512 Whh0]
    int col = i / 800, k = i - col * 800;
    float v = (k < 288) ? mem_Wih0[col * 288 + k] : mem_Whh[col * 512 + (k - 288)];
    Wm0[i] = (bf16)v;
    return;
  }
  i -= 1638400;
  if (i < 6291456) {    // Wm1..3: [2048][512 WihR | 512 Whh]
    int l = i >> 21;
    int r = i & 2097151;
    int col = r >> 10, k = r & 1023;
    float v = (k < 512) ? mem_WihR[(l * 2048 + col) * 512 + k]
                        : mem_Whh[((l + 1) * 2048 + col) * 512 + (k - 512)];
    Wm123[i] = (bf16)v;
    return;
  }
  i -= 6291456;
  if (i < 8192) { Wemb[i] = (bf16)emb_w[i]; return; }
  i -= 8192;
  if (i < 8192) { bc[i] = mem_bih[i] + mem_bhh[i]; return; }
  i -= 8192;
  if (i < 8192) { h_enc[i] = (bf16)enc_h0[i]; return; }   // enc slot 0
  i -= 8192;
  if (i < 65536) {                                        // mem slot 0, per layer
    int l = i >> 14, r = i & 16383;
    h_mem[l * HM_ELEMS + r] = (bf16)mem_h0[i];
    return;
  }
  i -= 65536;
  if (i < 401408) { fcw_bf[i] = (bf16)fc_w[i]; return; }
}

__global__ void pre_enc_kernel(const float* __restrict__ lang, const float* __restrict__ Wih,
    const float* __restrict__ bih, const float* __restrict__ bhh, float* __restrict__ pre)
{
  int idx = blockIdx.x * 256 + threadIdx.x;
  if (idx >= 64 * 32 * 1024) return;
  int col = idx & 1023, bm = idx >> 10;
  float acc = bih[col] + bhh[col];
  const float* lp = lang + bm * 14;
  const float* wp = Wih + col * 14;
#pragma unroll
  for (int k = 0; k < 14; ++k) acc += lp[k] * wp[k];
  pre[idx] = acc;
}

// ---------------------------------------------------------------------------
// conv stack (fp32, LDS-staged; conv1 is HBM-bound anyway)
// ---------------------------------------------------------------------------
__global__ void conv1_kernel(const float* __restrict__ img, const float* __restrict__ w,
                             const float* __restrict__ bias, float* __restrict__ out) {
  int bid = blockIdx.x;
  int n = bid / 11, oh = bid % 11;
  __shared__ float sIn[3 * 9 * 99];
  __shared__ float sW[16 * 243];
  int tid = threadIdx.x;
  for (int i = tid; i < 3888; i += 256) sW[i] = w[i];
  const float* ibase = img + (size_t)n * 3 * 99 * 99 + oh * 9 * 99;
  for (int i = tid; i < 2673; i += 256) {
    int c = i / 891, r = i - c * 891;
    sIn[i] = ibase[c * 9801 + r];
  }
  __syncthreads();
  if (tid < 176) {
    int oc = tid / 11, ow = tid % 11;
    float acc = bias[oc];
    const float* wp = sW + oc * 243;
#pragma unroll
    for (int c = 0; c < 3; ++c)
#pragma unroll
      for (int kh = 0; kh < 9; ++kh) {
        const float* ip = sIn + c * 891 + kh * 99 + ow * 9;
        const float* wq = wp + c * 81 + kh * 9;
#pragma unroll
        for (int kw = 0; kw < 9; ++kw) acc += ip[kw] * wq[kw];
      }
    out[((size_t)n * 16 + oc) * 121 + oh * 11 + ow] = fmaxf(acc, 0.f);
  }
}

__global__ void conv2_kernel(const float* __restrict__ in, const float* __restrict__ w,
                             const float* __restrict__ bias, float* __restrict__ out) {
  int n = blockIdx.x;
  __shared__ float sIn[16 * 121];
  __shared__ float sW[32 * 144];
  int tid = threadIdx.x;
  for (int i = tid; i < 4608; i += 256) sW[i] = w[i];
  for (int i = tid; i < 1936; i += 256) sIn[i] = in[(size_t)n * 1936 + i];
  __syncthreads();
  for (int o = tid; o < 2592; o += 256) {
    int oc = o / 81, r = o - oc * 81, ohh = r / 9, oww = r - (r / 9) * 9;
    float acc = bias[oc];
    const float* wp = sW + oc * 144;
#pragma unroll 4
    for (int c = 0; c < 16; ++c) {
      const float* ip = sIn + c * 121 + ohh * 11 + oww;
      const float* wq = wp + c * 9;
      acc += ip[0]*wq[0] + ip[1]*wq[1] + ip[2]*wq[2]
           + ip[11]*wq[3] + ip[12]*wq[4] + ip[13]*wq[5]
           + ip[22]*wq[6] + ip[23]*wq[7] + ip[24]*wq[8];
    }
    out[(size_t)n * 2592 + o] = fmaxf(acc, 0.f);
  }
}

__global__ void conv3_kernel(const float* __restrict__ in, const float* __restrict__ w,
                             const float* __restrict__ bias, float* __restrict__ out) {
  int n = blockIdx.x;
  __shared__ float sIn[32 * 81];
  __shared__ float sW[32 * 288];
  int tid = threadIdx.x;
  for (int i = tid; i < 9216; i += 256) sW[i] = w[i];
  for (int i = tid; i < 2592; i += 256) sIn[i] = in[(size_t)n * 2592 + i];
  __syncthreads();
  for (int o = tid; o < 1568; o += 256) {
    int oc = o / 49, r = o - oc * 49, ohh = r / 7, oww = r - (r / 7) * 7;
    float acc = bias[oc];
    const float* wp = sW + oc * 288;
#pragma unroll 4
    for (int c = 0; c < 32; ++c) {
      const float* ip = sIn + c * 81 + ohh * 9 + oww;
      const float* wq = wp + c * 9;
      acc += ip[0]*wq[0] + ip[1]*wq[1] + ip[2]*wq[2]
           + ip[9]*wq[3] + ip[10]*wq[4] + ip[11]*wq[5]
           + ip[18]*wq[6] + ip[19]*wq[7] + ip[20]*wq[8];
    }
    out[(size_t)n * 1568 + o] = fmaxf(acc, 0.f);
  }
}

// ---- fc: (2048x1568)@(1568x256) bf16 MFMA -> relu -> hidden[:, :256] (bf16)
__global__ __launch_bounds__(256) void fc_kernel(const float* __restrict__ a3,
    const bf16* __restrict__ wbf, const float* __restrict__ fc_b, bf16* __restrict__ hidden) {
  __shared__ bf16 sA[64 * 72];
  __shared__ bf16 sB[64 * 72];
  int bid = blockIdx.x, tid = threadIdx.x;
  int rg = bid >> 2, cg = bid & 3;
  int r0 = rg * 64, c0 = cg * 64;
  int lane = tid & 63, wv = tid >> 6, hsel = lane >> 5, ln31 = lane & 31;
  int wm = wv >> 1, wn = wv & 1;
  f32x16v acc = {};
  for (int kb = 0; kb < 1568; kb += 64) {
    __syncthreads();
    for (int i = tid; i < 512; i += 256) {
      int r = i >> 3, kk = (i & 7) * 8;
      int k = kb + kk;
      bf16x8 va = {}, vb = {};
      if (k < 1568) {
        const float* p = a3 + (size_t)(r0 + r) * 1568 + k;
#pragma unroll
        for (int j = 0; j < 8; ++j) va[j] = (bf16)p[j];
        vb = *(const bf16x8*)(wbf + (size_t)(c0 + r) * 1568 + k);
      }
      *(bf16x8*)(sA + r * 72 + kk) = va;
      *(bf16x8*)(sB + r * 72 + kk) = vb;
    }
    __syncthreads();
#pragma unroll
    for (int ks = 0; ks < 4; ++ks) {
      int k = ks * 16 + hsel * 8;
      bf16x8 a = *(const bf16x8*)(sA + (wm * 32 + ln31) * 72 + k);
      bf16x8 b = *(const bf16x8*)(sB + (wn * 32 + ln31) * 72 + k);
      acc = __builtin_amdgcn_mfma_f32_32x32x16_bf16(a, b, acc, 0, 0, 0);
    }
  }
  int cc = c0 + wn * 32 + ln31;
  float bv = fc_b[cc];
#pragma unroll
  for (int q = 0; q < 4; ++q)
#pragma unroll
    for (int s = 0; s < 4; ++s) {
      int m = 8 * q + 4 * hsel + s;
      int row = r0 + wm * 32 + m;
      hidden[(size_t)row * 288 + cc] = (bf16)fmaxf(acc[4 * q + s] + bv, 0.f);
    }
}

// ---------------------------------------------------------------------------
extern "C" void kernel_launch(void* const* d_in, const int* in_sizes, int n_in,
                              void* d_out, int out_size, void* d_ws, size_t ws_size,
                              hipStream_t stream)
{
  const float* img      = (const float*)d_in[0];
  const float* lang     = (const float*)d_in[1];
  const float* done     = (const float*)d_in[2];
  const int*   action   = (const int*)d_in[3];
  const float* enc_h0   = (const float*)d_in[4];
  const float* enc_c0   = (const float*)d_in[5];
  const float* mem_h0   = (const float*)d_in[6];
  const float* mem_c0   = (const float*)d_in[7];
  const float* conv1_w  = (const float*)d_in[8];
  const float* conv1_b  = (const float*)d_in[9];
  const float* conv2_w  = (const float*)d_in[10];
  const float* conv2_b  = (const float*)d_in[11];
  const float* conv3_w  = (const float*)d_in[12];
  const float* conv3_b  = (const float*)d_in[13];
  const float* fc_w     = (const float*)d_in[14];
  const float* fc_b     = (const float*)d_in[15];
  const float* enc_Wih  = (const float*)d_in[16];
  const float* enc_Whh  = (const float*)d_in[17];
  const float* enc_bih  = (const float*)d_in[18];
  const float* enc_bhh  = (const float*)d_in[19];
  const float* emb_w    = (const float*)d_in[20];
  const float* emb_b    = (const float*)d_in[21];
  const float* mem_Wih0 = (const float*)d_in[22];
  const float* mem_WihR = (const float*)d_in[23];
  const float* mem_Whh  = (const float*)d_in[24];
  const float* mem_bih  = (const float*)d_in[25];
  const float* mem_bhh  = (const float*)d_in[26];
  const float* actor_w  = (const float*)d_in[27];
  const float* actor_b  = (const float*)d_in[28];
  const float* critic_w = (const float*)d_in[29];
  const float* critic_b = (const float*)d_in[30];
  float* out = (float*)d_out;
  (void)in_sizes; (void)n_in; (void)out_size; (void)ws_size;

  char* wp = (char*)d_ws;
  auto alloc = [&](size_t b) { char* p = wp; wp += (b + 255) & ~(size_t)255; return p; };
  float* A1     = (float*)alloc(2048ull * 16 * 121 * 4);   // conv1 out (reused as A3)
  float* A2     = (float*)alloc(2048ull * 32 * 81 * 4);    // conv2 out
  bf16*  hidden = (bf16*) alloc(2048ull * 288 * 2);
  float* preenc = (float*)alloc(64ull * 32 * 1024 * 4);
  bf16*  Wenc   = (bf16*) alloc(1024ull * 256 * 2);
  bf16*  Wm0    = (bf16*) alloc(2048ull * 800 * 2);
  bf16*  Wm123  = (bf16*) alloc(3ull * 2048 * 1024 * 2);
  bf16*  Wemb   = (bf16*) alloc(32ull * 256 * 2);
  float* bc     = (float*)alloc(4ull * 2048 * 4);
  bf16*  h_enc  = (bf16*) alloc(65ull * 32 * 256 * 2);
  bf16*  h_mem  = (bf16*) alloc(4ull * HM_ELEMS * 2);
  bf16*  fcwbf  = (bf16*) alloc(256ull * 1568 * 2);
  int*   fl     = (int*)  alloc(4096);
  float* A3     = A1;   // conv3 out aliases conv1 out (dead by then)

  prep_kernel<<<33920, 256, 0, stream>>>(enc_Whh, mem_Wih0, mem_WihR, mem_Whh, emb_w,
      mem_bih, mem_bhh, enc_h0, mem_h0, fc_w, Wenc, Wm0, Wm123, Wemb, bc, h_enc, h_mem, fcwbf);
  pre_enc_kernel<<<8192, 256, 0, stream>>>(lang, enc_Wih, enc_bih, enc_bhh, preenc);
  conv1_kernel<<<2048 * 11, 256, 0, stream>>>(img, conv1_w, conv1_b, A1);
  conv2_kernel<<<2048, 256, 0, stream>>>(A1, conv2_w, conv2_b, A2);
  conv3_kernel<<<2048, 256, 0, stream>>>(A2, conv3_w, conv3_b, A3);
  fc_kernel<<<128, 256, 0, stream>>>(A3, fcwbf, fc_b, hidden);
  hipMemsetAsync(fl, 0, 4096, stream);

  PipeP P;
  P.Wenc = Wenc; P.Wm0 = Wm0; P.Wm1 = Wm123;
  P.Wm2 = Wm123 + 2048 * 1024; P.Wm3 = Wm123 + 2ull * 2048 * 1024;
  P.Wemb = Wemb; P.pre_enc = preenc; P.bc = bc; P.done = done; P.emb_b = emb_b;
  P.enc_c0 = enc_c0; P.mem_c0 = mem_c0; P.hidden = hidden; P.h_enc = h_enc; P.h_mem = h_mem;
  P.actor_w = actor_w; P.actor_b = actor_b; P.critic_w = critic_w; P.critic_b = critic_b;
  P.action = action; P.out = out; P.fl = fl;

  (void)hipFuncSetAttribute((const void*)pipeline_kernel,
      hipFuncAttributeMaxDynamicSharedMemorySize, 104448);
  pipeline_kernel<<<146, 256, 104448, stream>>>(P);
}

// Round 2
// 1516.216 us; speedup vs baseline: 1.3973x; 1.3973x over previous
//
#include <hip/hip_runtime.h>

// ---------------------------------------------------------------------------
// Agent forward pass on MI355X — round 2.
// Changes vs round 1:
//  * No memory fences in the persistent pipeline (buffer_inv/buffer_wbl2 were
//    ~18 us/step). Cross-block data goes through IF via agent-scope relaxed
//    atomic stores; consumers use plain vector loads (addresses are
//    write-once, read-after-flag => no stale lines possible).
//  * 16 blocks per mem layer (32 units each), flags padded to 16 B.
//  * conv1 rewritten as disjoint-patch MFMA GEMM (was ~850 us of scalar LDS).
// ---------------------------------------------------------------------------

typedef __bf16 bf16;
typedef __bf16 bf16x8 __attribute__((ext_vector_type(8)));
typedef float f32x4v __attribute__((ext_vector_type(4)));
typedef float f32x16v __attribute__((ext_vector_type(16)));
typedef unsigned int u32;

#define SCOPE_AGENT __HIP_MEMORY_SCOPE_AGENT
#define HM_ELEMS (65 * 32 * 512)   // one mem-layer h array: [65 slots][32][512]

__device__ __forceinline__ float sigf_(float x) {
  x = fminf(fmaxf(x, -30.f), 30.f);
  return 1.f / (1.f + __expf(-x));
}
__device__ __forceinline__ float tanhf_(float x) {
  x = fminf(fmaxf(x, -15.f), 15.f);
  float e = __expf(2.f * x);
  return (e - 1.f) / (e + 1.f);
}
__device__ __forceinline__ void wait_ge(int* f, int need) {
  while (__hip_atomic_load(f, __ATOMIC_RELAXED, SCOPE_AGENT) < need)
    __builtin_amdgcn_s_sleep(1);
}
__device__ __forceinline__ void flag_add(int* f) {
  __hip_atomic_fetch_add(f, 1, __ATOMIC_RELAXED, SCOPE_AGENT);
}
__device__ __forceinline__ void store_pair(bf16* base, size_t elem_idx, float a, float b) {
  unsigned short lo = __builtin_bit_cast(unsigned short, (bf16)a);
  unsigned short hi = __builtin_bit_cast(unsigned short, (bf16)b);
  u32 pk = (u32)lo | ((u32)hi << 16);
  __hip_atomic_store((u32*)base + (elem_idx >> 1), pk, __ATOMIC_RELAXED, SCOPE_AGENT);
}

// stage 32 rows x KLEN bf16 into swizzled LDS A-buffer at column offset koff.
// maskrow != null: zero row m when maskrow[m] != 0 (done flag -> reset h).
template<int KS_PAD, int KLEN>
__device__ __forceinline__ void stage32(bf16* __restrict__ dst, const bf16* __restrict__ src,
                                        int koff, const float* __restrict__ maskrow, int tid) {
  constexpr int VPR = KLEN / 8;
  for (int i = tid; i < 32 * VPR; i += 256) {
    int m = i / VPR, j = i - m * VPR;
    uint4 v = *(const uint4*)(src + m * KLEN + j * 8);
    if (maskrow != nullptr && maskrow[m] != 0.0f) { v.x = 0u; v.y = 0u; v.z = 0u; v.w = 0u; }
    int kd = koff + j * 8;
    *(uint4*)(dst + m * KS_PAD + (kd ^ ((m & 15) * 8))) = v;
  }
}

// ---------------------------------------------------------------------------
// LSTM scan block. Owns 32 hidden units (= 128 gate cols, 4 tiles = gates
// i,f,g,o x 32 units). 4 waves split K 4-ways, each covering all 4 gate tiles.
// Weights VGPR-resident; gates reduced via LDS partials (stride 33,
// conflict-free); c in LDS fp32; h written via agent-scope atomic u32 pairs.
// ---------------------------------------------------------------------------
template<int KS_PAD, int NKT, int NKS, bool GUARD, int HDIM, bool PRE, int XLEN>
__device__ void scan_body(const bf16* __restrict__ Wrows, const float* __restrict__ biasf,
    const bf16* __restrict__ xbase, const bf16* __restrict__ hbase, bf16* __restrict__ hout,
    const float* __restrict__ cinit, const float* __restrict__ done,
    int* flag_own, int need_own, int* flag_x, int need_x, int* flag_post,
    int u0, int tid, char* smem)
{
  constexpr int KW = NKT * 16;                         // weight row length (elems)
  bf16* Abuf = (bf16*)smem;                            // [32][KS_PAD] swizzled
  float* partial = (float*)(smem + 32 * KS_PAD * 2);   // [4 kq][128 col][33]
  float* cl = partial + 4 * 128 * 33;                  // [32 m][32 u]
  const int lane = tid & 63, wv = tid >> 6;
  const int hsel = lane >> 5, ln31 = lane & 31;
  const int ks0 = wv * NKS;

  // ---- preload this wave's B-fragments of W (time-invariant) ----
  bf16x8 Wreg[4][NKS];
#pragma unroll
  for (int g = 0; g < 4; ++g) {
    int row = g * HDIM + u0 + ln31;
#pragma unroll
    for (int ks = 0; ks < NKS; ++ks) {
      bf16x8 w8 = {};
      if (!GUARD || (ks0 + ks) < NKT)
        w8 = *(const bf16x8*)(Wrows + (size_t)row * KW + (ks0 + ks) * 16 + hsel * 8);
      Wreg[g][ks] = w8;
    }
  }
  for (int i = tid; i < 1024; i += 256)
    cl[i] = cinit[(i >> 5) * HDIM + u0 + (i & 31)];

  for (int t = 0; t < 64; ++t) {
    if (tid == 0) {
      if (t > 0) wait_ge(flag_own + (t - 1) * 4, need_own);
      if (need_x > 0) wait_ge(flag_x + t * 4, need_x);
    }
    __syncthreads();
    if constexpr (XLEN > 0)
      stage32<KS_PAD, (XLEN > 0 ? XLEN : 8)>(Abuf, xbase + (size_t)t * 32 * XLEN, 0, nullptr, tid);
    stage32<KS_PAD, HDIM>(Abuf, hbase + (size_t)t * 32 * HDIM, XLEN, done + t * 32, tid);
    __syncthreads();

    f32x16v acc[4] = {};
#pragma unroll
    for (int ks = 0; ks < NKS; ++ks) {
      if (!GUARD || (ks0 + ks) < NKT) {
        int k = (ks0 + ks) * 16 + hsel * 8;
        bf16x8 a = *(const bf16x8*)(Abuf + ln31 * KS_PAD + (k ^ ((ln31 & 15) * 8)));
#pragma unroll
        for (int g = 0; g < 4; ++g)
          acc[g] = __builtin_amdgcn_mfma_f32_32x32x16_bf16(a, Wreg[g][ks], acc[g], 0, 0, 0);
      }
    }
    // partial[kq=wv][col = g*32 + ln31][m]; C/D: col=lane&31, m=(reg&3)+8*(reg>>2)+4*hsel
#pragma unroll
    for (int g = 0; g < 4; ++g) {
      float* pp = partial + (wv * 128 + g * 32 + ln31) * 33 + 4 * hsel;
#pragma unroll
      for (int q = 0; q < 4; ++q)
#pragma unroll
        for (int s = 0; s < 4; ++s)
          pp[8 * q + s] = acc[g][4 * q + s];
    }
    __syncthreads();
    // pointwise: 32 m x 16 unit-pairs
    for (int p = tid; p < 512; p += 256) {
      int m = p >> 4, up = (p & 15) * 2;
      float dn = done[t * 32 + m];
      float hv[2];
#pragma unroll
      for (int j = 0; j < 2; ++j) {
        int u = up + j;
        float gg[4];
#pragma unroll
        for (int g = 0; g < 4; ++g) {
          int col = g * 32 + u;
          float s = partial[col * 33 + m] + partial[(128 + col) * 33 + m]
                  + partial[(256 + col) * 33 + m] + partial[(384 + col) * 33 + m];
          if (PRE) s += biasf[(size_t)(t * 32 + m) * (4 * HDIM) + g * HDIM + u0 + u];
          else     s += biasf[g * HDIM + u0 + u];
          gg[g] = s;
        }
        int ci = m * 32 + u;
        float cold = cl[ci] * (1.0f - dn);
        float cn = sigf_(gg[1]) * cold + sigf_(gg[0]) * tanhf_(gg[2]);
        cl[ci] = cn;
        hv[j] = sigf_(gg[3]) * tanhf_(cn);
      }
      store_pair(hout, ((size_t)(t + 1) * 32 + m) * HDIM + u0 + up, hv[0], hv[1]);
    }
    __syncthreads();
    if (tid == 0) flag_add(flag_post + t * 4);
  }
}

// ---- emb: lang_e[t] = relu(lang_h[t] @ emb_w.T + emb_b) -> hidden[:,256:288]
__device__ void emb_body(const bf16* __restrict__ Wemb, const float* __restrict__ emb_b,
    const bf16* __restrict__ h_enc, bf16* __restrict__ hidden,
    int* fle, int* flb, int t0, int tid, char* smem)
{
  bf16* Abuf = (bf16*)smem;                         // 32x256
  float* partial = (float*)(smem + 32 * 256 * 2);   // [4][32][33]
  const int lane = tid & 63, wv = tid >> 6;
  const int hsel = lane >> 5, ln31 = lane & 31;
  const int ks0 = wv * 4;
  bf16x8 Wreg[4];
#pragma unroll
  for (int ks = 0; ks < 4; ++ks)
    Wreg[ks] = *(const bf16x8*)(Wemb + ln31 * 256 + (ks0 + ks) * 16 + hsel * 8);
  for (int t = t0; t < 64; t += 4) {
    if (tid == 0) wait_ge(fle + t * 4, 8);
    __syncthreads();
    stage32<256, 256>(Abuf, h_enc + (size_t)(t + 1) * 32 * 256, 0, nullptr, tid);
    __syncthreads();
    f32x16v acc = {};
#pragma unroll
    for (int ks = 0; ks < 4; ++ks) {
      int k = (ks0 + ks) * 16 + hsel * 8;
      bf16x8 a = *(const bf16x8*)(Abuf + ln31 * 256 + (k ^ ((ln31 & 15) * 8)));
      acc = __builtin_amdgcn_mfma_f32_32x32x16_bf16(a, Wreg[ks], acc, 0, 0, 0);
    }
    float* pp = partial + (wv * 32 + ln31) * 33 + 4 * hsel;
#pragma unroll
    for (int q = 0; q < 4; ++q)
#pragma unroll
      for (int s = 0; s < 4; ++s)
        pp[8 * q + s] = acc[4 * q + s];
    __syncthreads();
    for (int p = tid; p < 512; p += 256) {
      int m = p >> 4, np = (p & 15) * 2;
      float v[2];
#pragma unroll
      for (int j = 0; j < 2; ++j) {
        int col = np + j;
        float s = partial[col * 33 + m] + partial[(32 + col) * 33 + m]
                + partial[(64 + col) * 33 + m] + partial[(96 + col) * 33 + m] + emb_b[col];
        v[j] = fmaxf(s, 0.f);
      }
      store_pair(hidden, (size_t)(t * 32 + m) * 288 + 256 + np, v[0], v[1]);
    }
    __syncthreads();
    if (tid == 0) flag_add(flb + t * 4);
  }
}

// ---- heads: logits, log_softmax, entropy, value
__device__ void heads_body(const bf16* __restrict__ h3, const float* __restrict__ actor_w,
    const float* __restrict__ actor_b, const float* __restrict__ critic_w,
    const float* __restrict__ critic_b, const int* __restrict__ action,
    float* __restrict__ out, int* fl3, int t0, int tid, char* smem)
{
  float* hS = (float*)smem;       // [32][520]
  float* lg = hS + 32 * 520;      // [32][8]
  float* vp = lg + 256;           // [32][8]
  const int b = tid >> 3, c = tid & 7;
  for (int t = t0; t < 64; t += 8) {
    if (tid == 0) wait_ge(fl3 + t * 4, 16);
    __syncthreads();
    for (int i = tid; i < 2048; i += 256) {
      int m = i >> 6, kb = (i & 63) * 8;
      bf16x8 v = *(const bf16x8*)(h3 + ((size_t)(t + 1) * 32 + m) * 512 + kb);
#pragma unroll
      for (int j = 0; j < 8; ++j) hS[m * 520 + kb + j] = (float)v[j];
    }
    __syncthreads();
    float acc = actor_b[c];
    float va = 0.f;
#pragma unroll 4
    for (int k = 0; k < 512; k += 4) {
      f32x4v hv = *(const f32x4v*)(hS + b * 520 + k);
      f32x4v wv4 = *(const f32x4v*)(actor_w + c * 512 + k);
      acc += hv[0]*wv4[0] + hv[1]*wv4[1] + hv[2]*wv4[2] + hv[3]*wv4[3];
    }
    for (int k = c * 64; k < c * 64 + 64; k += 4) {
      f32x4v hv = *(const f32x4v*)(hS + b * 520 + k);
      f32x4v wv4 = *(const f32x4v*)(critic_w + k);
      va += hv[0]*wv4[0] + hv[1]*wv4[1] + hv[2]*wv4[2] + hv[3]*wv4[3];
    }
    lg[b * 8 + c] = acc;
    vp[b * 8 + c] = va;
    __syncthreads();
    if (tid < 32) {
      const float* L = lg + tid * 8;
      float mx = L[0];
#pragma unroll
      for (int i = 1; i < 8; ++i) mx = fmaxf(mx, L[i]);
      float s = 0.f;
#pragma unroll
      for (int i = 0; i < 8; ++i) s += __expf(L[i] - mx);
      float lse = mx + __logf(s);
      float ent = 0.f;
#pragma unroll
      for (int i = 0; i < 8; ++i) { float lp = L[i] - lse; ent -= __expf(lp) * lp; }
      int a = action[t * 32 + tid];
      a = a < 0 ? 0 : (a > 7 ? 7 : a);
      float val = critic_b[0];
#pragma unroll
      for (int i = 0; i < 8; ++i) val += vp[tid * 8 + i];
      float* o = out + (size_t)(t * 32 + tid) * 3;
      o[0] = L[a] - lse; o[1] = ent; o[2] = val;
    }
    __syncthreads();
  }
}

struct PipeP {
  const bf16 *Wenc, *Wm0, *Wm1, *Wm2, *Wm3, *Wemb;
  const float *pre_enc, *bc, *done, *emb_b, *enc_c0, *mem_c0;
  bf16 *hidden, *h_enc, *h_mem;
  const float *actor_w, *actor_b, *critic_w, *critic_b;
  const int *action;
  float *out;
  int *fl;
};

// grid: 0..63 mem (16 blocks x 4 layers), 64..71 enc, 72..75 emb, 76..83 heads
__global__ __launch_bounds__(256, 1) void pipeline_kernel(PipeP P) {
  extern __shared__ char smem[];
  const int bid = blockIdx.x, tid = threadIdx.x;
  int* flm = P.fl;             // [4][64][4]
  int* fle = P.fl + 1024;      // [64][4]
  int* flb = P.fl + 1280;      // [64][4]
  if (bid < 64) {
    int l = bid >> 4, u0 = (bid & 15) * 32;
    bf16* hown = P.h_mem + (size_t)l * HM_ELEMS;
    if (l == 0) {
      scan_body<1024, 50, 13, true, 512, false, 288>(P.Wm0, P.bc, P.hidden, hown, hown,
          P.mem_c0, P.done, flm, 16, flb, 1, flm, u0, tid, smem);
    } else {
      const bf16* W = (l == 1) ? P.Wm1 : (l == 2) ? P.Wm2 : P.Wm3;
      scan_body<1024, 64, 16, false, 512, false, 512>(W, P.bc + l * 2048,
          P.h_mem + (size_t)(l - 1) * HM_ELEMS + 32 * 512, hown, hown,
          P.mem_c0 + l * 32 * 512, P.done,
          flm + l * 256, 16, flm + (l - 1) * 256, 16, flm + l * 256, u0, tid, smem);
    }
  } else if (bid < 72) {
    int u0 = (bid - 64) * 32;
    scan_body<256, 16, 4, false, 256, true, 0>(P.Wenc, P.pre_enc, nullptr, P.h_enc, P.h_enc,
        P.enc_c0, P.done, fle, 8, nullptr, 0, fle, u0, tid, smem);
  } else if (bid < 76) {
    emb_body(P.Wemb, P.emb_b, P.h_enc, P.hidden, fle, flb, bid - 72, tid, smem);
  } else {
    heads_body(P.h_mem + 3ull * HM_ELEMS, P.actor_w, P.actor_b, P.critic_w, P.critic_b,
        P.action, P.out, flm + 768, bid - 76, tid, smem);
  }
}

// ---------------------------------------------------------------------------
// prep: weight conversions / concat layouts / initial h slots
// ---------------------------------------------------------------------------
__global__ void prep_kernel(
    const float* __restrict__ enc_Whh, const float* __restrict__ mem_Wih0,
    const float* __restrict__ mem_WihR, const float* __restrict__ mem_Whh,
    const float* __restrict__ emb_w, const float* __restrict__ mem_bih,
    const float* __restrict__ mem_bhh, const float* __restrict__ enc_h0,
    const float* __restrict__ mem_h0, const float* __restrict__ fc_w,
    const float* __restrict__ conv1_w,
    bf16* __restrict__ Wenc, bf16* __restrict__ Wm0, bf16* __restrict__ Wm123,
    bf16* __restrict__ Wemb, float* __restrict__ bc,
    bf16* __restrict__ h_enc, bf16* __restrict__ h_mem, bf16* __restrict__ fcw_bf,
    bf16* __restrict__ w1bf)
{
  int i = blockIdx.x * 256 + threadIdx.x;
  if (i < 262144) { Wenc[i] = (bf16)enc_Whh[i]; return; }
  i -= 262144;
  if (i < 1638400) {    // Wm0: [2048][288 Wih0 | 512 Whh0]
    int col = i / 800, k = i - col * 800;
    float v = (k < 288) ? mem_Wih0[col * 288 + k] : mem_Whh[col * 512 + (k - 288)];
    Wm0[i] = (bf16)v;
    return;
  }
  i -= 1638400;
  if (i < 6291456) {    // Wm1..3: [2048][512 WihR | 512 Whh]
    int l = i >> 21;
    int r = i & 2097151;
    int col = r >> 10, k = r & 1023;
    float v = (k < 512) ? mem_WihR[((size_t)l * 2048 + col) * 512 + k]
                        : mem_Whh[((size_t)(l + 1) * 2048 + col) * 512 + (k - 512)];
    Wm123[i] = (bf16)v;
    return;
  }
  i -= 6291456;
  if (i < 8192) { Wemb[i] = (bf16)emb_w[i]; return; }
  i -= 8192;
  if (i < 8192) { bc[i] = mem_bih[i] + mem_bhh[i]; return; }
  i -= 8192;
  if (i < 8192) { h_enc[i] = (bf16)enc_h0[i]; return; }   // enc slot 0
  i -= 8192;
  if (i < 65536) {                                        // mem slot 0, per layer
    int l = i >> 14, r = i & 16383;
    h_mem[(size_t)l * HM_ELEMS + r] = (bf16)mem_h0[i];
    return;
  }
  i -= 65536;
  if (i < 401408) { fcw_bf[i] = (bf16)fc_w[i]; return; }
  i -= 401408;
  if (i < 4096) {       // conv1 weights as [16 oc][256 k] bf16, zero-padded K
    int oc = i >> 8, k = i & 255;
    w1bf[i] = (k < 243) ? (bf16)conv1_w[oc * 243 + k] : (bf16)0.0f;
    return;
  }
}

__global__ void pre_enc_kernel(const float* __restrict__ lang, const float* __restrict__ Wih,
    const float* __restrict__ bih, const float* __restrict__ bhh, float* __restrict__ pre)
{
  int idx = blockIdx.x * 256 + threadIdx.x;
  if (idx >= 64 * 32 * 1024) return;
  int col = idx & 1023, bm = idx >> 10;
  float acc = bih[col] + bhh[col];
  const float* lp = lang + bm * 14;
  const float* wp = Wih + col * 14;
#pragma unroll
  for (int k = 0; k < 14; ++k) acc += lp[k] * wp[k];
  pre[idx] = acc;
}

// ---------------------------------------------------------------------------
// conv1 as MFMA GEMM: stride 9 == kernel 9 -> disjoint patches.
// Per image: A = patches [121(pad128) x 243(pad256)], B = W^T, 16x16x32 bf16.
// ---------------------------------------------------------------------------
__global__ __launch_bounds__(256) void conv1_mfma(const float* __restrict__ img,
    const bf16* __restrict__ w1bf, const float* __restrict__ bias, float* __restrict__ out) {
  __shared__ bf16 sP[128 * 256];   // 64 KB patch matrix, XOR-swizzled
  const int n = blockIdx.x, tid = threadIdx.x;
  const int lane = tid & 63, wv = tid >> 6;
  for (int i = tid; i < 4096; i += 256) ((uint4*)sP)[i] = uint4{0u, 0u, 0u, 0u};
  __syncthreads();
  const float* ib = img + (size_t)n * 29403;
  for (int e = tid; e < 29403; e += 256) {
    int c = e / 9801, r = e - c * 9801;
    int h = r / 99, w = r - h * 99;
    int oh = h / 9, kh = h - oh * 9;
    int ow = w / 9, kw = w - ow * 9;
    int p = oh * 11 + ow;
    int k = c * 81 + kh * 9 + kw;
    sP[p * 256 + (k ^ ((p & 15) * 8))] = (bf16)ib[e];
  }
  __syncthreads();
  const int oc = lane & 15, kg = lane >> 4;   // kg in [0,4)
  bf16x8 bfr[8];
#pragma unroll
  for (int ks = 0; ks < 8; ++ks)
    bfr[ks] = *(const bf16x8*)(w1bf + oc * 256 + ks * 32 + kg * 8);
  const float bv = bias[oc];
#pragma unroll
  for (int mt2 = 0; mt2 < 2; ++mt2) {
    int mt = wv * 2 + mt2;
    int p = mt * 16 + (lane & 15);
    f32x4v acc = {};
#pragma unroll
    for (int ks = 0; ks < 8; ++ks) {
      int k0 = ks * 32 + kg * 8;
      bf16x8 a = *(const bf16x8*)(sP + p * 256 + (k0 ^ ((p & 15) * 8)));
      acc = __builtin_amdgcn_mfma_f32_16x16x32_bf16(a, bfr[ks], acc, 0, 0, 0);
    }
    // C/D 16x16: col=lane&15 (=oc), row=(lane>>4)*4+s (=patch)
#pragma unroll
    for (int s = 0; s < 4; ++s) {
      int pm = mt * 16 + (lane >> 4) * 4 + s;
      if (pm < 121)
        out[((size_t)n * 16 + oc) * 121 + pm] = fmaxf(acc[s] + bv, 0.f);
    }
  }
}

__global__ void conv2_kernel(const float* __restrict__ in, const float* __restrict__ w,
                             const float* __restrict__ bias, float* __restrict__ out) {
  int n = blockIdx.x;
  __shared__ float sIn[16 * 121];
  __shared__ float sW[32 * 144];
  int tid = threadIdx.x;
  for (int i = tid; i < 4608; i += 256) sW[i] = w[i];
  for (int i = tid; i < 1936; i += 256) sIn[i] = in[(size_t)n * 1936 + i];
  __syncthreads();
  for (int o = tid; o < 2592; o += 256) {
    int oc = o / 81, r = o - oc * 81, ohh = r / 9, oww = r - (r / 9) * 9;
    float acc = bias[oc];
    const float* wp = sW + oc * 144;
#pragma unroll 4
    for (int c = 0; c < 16; ++c) {
      const float* ip = sIn + c * 121 + ohh * 11 + oww;
      const float* wq = wp + c * 9;
      acc += ip[0]*wq[0] + ip[1]*wq[1] + ip[2]*wq[2]
           + ip[11]*wq[3] + ip[12]*wq[4] + ip[13]*wq[5]
           + ip[22]*wq[6] + ip[23]*wq[7] + ip[24]*wq[8];
    }
    out[(size_t)n * 2592 + o] = fmaxf(acc, 0.f);
  }
}

__global__ void conv3_kernel(const float* __restrict__ in, const float* __restrict__ w,
                             const float* __restrict__ bias, float* __restrict__ out) {
  int n = blockIdx.x;
  __shared__ float sIn[32 * 81];
  __shared__ float sW[32 * 288];
  int tid = threadIdx.x;
  for (int i = tid; i < 9216; i += 256) sW[i] = w[i];
  for (int i = tid; i < 2592; i += 256) sIn[i] = in[(size_t)n * 2592 + i];
  __syncthreads();
  for (int o = tid; o < 1568; o += 256) {
    int oc = o / 49, r = o - oc * 49, ohh = r / 7, oww = r - (r / 7) * 7;
    float acc = bias[oc];
    const float* wp = sW + oc * 288;
#pragma unroll 4
    for (int c = 0; c < 32; ++c) {
      const float* ip = sIn + c * 81 + ohh * 9 + oww;
      const float* wq = wp + c * 9;
      acc += ip[0]*wq[0] + ip[1]*wq[1] + ip[2]*wq[2]
           + ip[9]*wq[3] + ip[10]*wq[4] + ip[11]*wq[5]
           + ip[18]*wq[6] + ip[19]*wq[7] + ip[20]*wq[8];
    }
    out[(size_t)n * 1568 + o] = fmaxf(acc, 0.f);
  }
}

// ---- fc: (2048x1568)@(1568x256) bf16 MFMA -> relu -> hidden[:, :256] (bf16)
__global__ __launch_bounds__(256) void fc_kernel(const float* __restrict__ a3,
    const bf16* __restrict__ wbf, const float* __restrict__ fc_b, bf16* __restrict__ hidden) {
  __shared__ bf16 sA[64 * 72];
  __shared__ bf16 sB[64 * 72];
  int bid = blockIdx.x, tid = threadIdx.x;
  int rg = bid >> 2, cg = bid & 3;
  int r0 = rg * 64, c0 = cg * 64;
  int lane = tid & 63, wv = tid >> 6, hsel = lane >> 5, ln31 = lane & 31;
  int wm = wv >> 1, wn = wv & 1;
  f32x16v acc = {};
  for (int kb = 0; kb < 1568; kb += 64) {
    __syncthreads();
    for (int i = tid; i < 512; i += 256) {
      int r = i >> 3, kk = (i & 7) * 8;
      int k = kb + kk;
      bf16x8 va = {}, vb = {};
      if (k < 1568) {
        const float* p = a3 + (size_t)(r0 + r) * 1568 + k;
#pragma unroll
        for (int j = 0; j < 8; ++j) va[j] = (bf16)p[j];
        vb = *(const bf16x8*)(wbf + (size_t)(c0 + r) * 1568 + k);
      }
      *(bf16x8*)(sA + r * 72 + kk) = va;
      *(bf16x8*)(sB + r * 72 + kk) = vb;
    }
    __syncthreads();
#pragma unroll
    for (int ks = 0; ks < 4; ++ks) {
      int k = ks * 16 + hsel * 8;
      bf16x8 a = *(const bf16x8*)(sA + (wm * 32 + ln31) * 72 + k);
      bf16x8 b = *(const bf16x8*)(sB + (wn * 32 + ln31) * 72 + k);
      acc = __builtin_amdgcn_mfma_f32_32x32x16_bf16(a, b, acc, 0, 0, 0);
    }
  }
  int cc = c0 + wn * 32 + ln31;
  float bv = fc_b[cc];
#pragma unroll
  for (int q = 0; q < 4; ++q)
#pragma unroll
    for (int s = 0; s < 4; ++s) {
      int m = 8 * q + 4 * hsel + s;
      int row = r0 + wm * 32 + m;
      hidden[(size_t)row * 288 + cc] = (bf16)fmaxf(acc[4 * q + s] + bv, 0.f);
    }
}

// ---------------------------------------------------------------------------
extern "C" void kernel_launch(void* const* d_in, const int* in_sizes, int n_in,
                              void* d_out, int out_size, void* d_ws, size_t ws_size,
                              hipStream_t stream)
{
  const float* img      = (const float*)d_in[0];
  const float* lang     = (const float*)d_in[1];
  const float* done     = (const float*)d_in[2];
  const int*   action   = (const int*)d_in[3];
  const float* enc_h0   = (const float*)d_in[4];
  const float* enc_c0   = (const float*)d_in[5];
  const float* mem_h0   = (const float*)d_in[6];
  const float* mem_c0   = (const float*)d_in[7];
  const float* conv1_w  = (const float*)d_in[8];
  const float* conv1_b  = (const float*)d_in[9];
  const float* conv2_w  = (const float*)d_in[10];
  const float* conv2_b  = (const float*)d_in[11];
  const float* conv3_w  = (const float*)d_in[12];
  const float* conv3_b  = (const float*)d_in[13];
  const float* fc_w     = (const float*)d_in[14];
  const float* fc_b     = (const float*)d_in[15];
  const float* enc_Wih  = (const float*)d_in[16];
  const float* enc_Whh  = (const float*)d_in[17];
  const float* enc_bih  = (const float*)d_in[18];
  const float* enc_bhh  = (const float*)d_in[19];
  const float* emb_w    = (const float*)d_in[20];
  const float* emb_b    = (const float*)d_in[21];
  const float* mem_Wih0 = (const float*)d_in[22];
  const float* mem_WihR = (const float*)d_in[23];
  const float* mem_Whh  = (const float*)d_in[24];
  const float* mem_bih  = (const float*)d_in[25];
  const float* mem_bhh  = (const float*)d_in[26];
  const float* actor_w  = (const float*)d_in[27];
  const float* actor_b  = (const float*)d_in[28];
  const float* critic_w = (const float*)d_in[29];
  const float* critic_b = (const float*)d_in[30];
  float* out = (float*)d_out;
  (void)in_sizes; (void)n_in; (void)out_size; (void)ws_size;

  char* wp = (char*)d_ws;
  auto alloc = [&](size_t b) { char* p = wp; wp += (b + 255) & ~(size_t)255; return p; };
  float* A1     = (float*)alloc(2048ull * 16 * 121 * 4);   // conv1 out (reused as A3)
  float* A2     = (float*)alloc(2048ull * 32 * 81 * 4);    // conv2 out
  bf16*  hidden = (bf16*) alloc(2048ull * 288 * 2);
  float* preenc = (float*)alloc(64ull * 32 * 1024 * 4);
  bf16*  Wenc   = (bf16*) alloc(1024ull * 256 * 2);
  bf16*  Wm0    = (bf16*) alloc(2048ull * 800 * 2);
  bf16*  Wm123  = (bf16*) alloc(3ull * 2048 * 1024 * 2);
  bf16*  Wemb   = (bf16*) alloc(32ull * 256 * 2);
  float* bc     = (float*)alloc(4ull * 2048 * 4);
  bf16*  h_enc  = (bf16*) alloc(65ull * 32 * 256 * 2);
  bf16*  h_mem  = (bf16*) alloc(4ull * HM_ELEMS * 2);
  bf16*  fcwbf  = (bf16*) alloc(256ull * 1568 * 2);
  bf16*  w1bf   = (bf16*) alloc(16ull * 256 * 2);
  int*   fl     = (int*)  alloc(8192);
  float* A3     = A1;   // conv3 out aliases conv1 out (dead by then)

  prep_kernel<<<33936, 256, 0, stream>>>(enc_Whh, mem_Wih0, mem_WihR, mem_Whh, emb_w,
      mem_bih, mem_bhh, enc_h0, mem_h0, fc_w, conv1_w,
      Wenc, Wm0, Wm123, Wemb, bc, h_enc, h_mem, fcwbf, w1bf);
  pre_enc_kernel<<<8192, 256, 0, stream>>>(lang, enc_Wih, enc_bih, enc_bhh, preenc);
  conv1_mfma<<<2048, 256, 0, stream>>>(img, w1bf, conv1_b, A1);
  conv2_kernel<<<2048, 256, 0, stream>>>(A1, conv2_w, conv2_b, A2);
  conv3_kernel<<<2048, 256, 0, stream>>>(A2, conv3_w, conv3_b, A3);
  fc_kernel<<<128, 256, 0, stream>>>(A3, fcwbf, fc_b, hidden);
  hipMemsetAsync(fl, 0, 6144, stream);

  PipeP P;
  P.Wenc = Wenc; P.Wm0 = Wm0; P.Wm1 = Wm123;
  P.Wm2 = Wm123 + 2048ull * 1024; P.Wm3 = Wm123 + 2ull * 2048 * 1024;
  P.Wemb = Wemb; P.pre_enc = preenc; P.bc = bc; P.done = done; P.emb_b = emb_b;
  P.enc_c0 = enc_c0; P.mem_c0 = mem_c0; P.hidden = hidden; P.h_enc = h_enc; P.h_mem = h_mem;
  P.actor_w = actor_w; P.actor_b = actor_b; P.critic_w = critic_w; P.critic_b = critic_b;
  P.action = action; P.out = out; P.fl = fl;

  (void)hipFuncSetAttribute((const void*)pipeline_kernel,
      hipFuncAttributeMaxDynamicSharedMemorySize, 137216);
  pipeline_kernel<<<84, 256, 137216, stream>>>(P);
}

// Round 3
// 1295.672 us; speedup vs baseline: 1.6351x; 1.1702x over previous
//
#include <hip/hip_runtime.h>

// ---------------------------------------------------------------------------
// Agent forward pass on MI355X — round 3.
//  * LSTM weights pinned in AGPRs (inline-asm mfma, B operand "a") — r2's
//    compiler rematerialized 256 KB/block/step of weight loads (VGPR=208<256).
//  * Activations staged global->LDS via global_load_lds dwordx4; h stored
//    chunk-XOR-swizzled in global so linear DMA yields conflict-free ds_read.
//  * Per-block flag slots + lane-parallel poll (no atomic-RMW serialization).
//  * conv2/conv3 register-tiled (0.5 LDS reads/FMA vs 2.0).
// ---------------------------------------------------------------------------

typedef __bf16 bf16;
typedef __bf16 bf16x8 __attribute__((ext_vector_type(8)));
typedef int v4i __attribute__((ext_vector_type(4)));
typedef float f32x4v __attribute__((ext_vector_type(4)));
typedef float f32x16v __attribute__((ext_vector_type(16)));
typedef unsigned int u32;

#define SCOPE_AGENT __HIP_MEMORY_SCOPE_AGENT
#define HM_ELEMS (65 * 32 * 512)

// MFMA via asm so B can live in AGPR. s_nop 2 covers VALU->MFMA SrcA/SrcC.
#define MFMA_AB(acc_, va_, wa_) \
  asm("s_nop 2\n\tv_mfma_f32_32x32x16_bf16 %0, %1, %2, %0" \
      : "+v"(acc_) : "v"(va_), "a"(wa_))
// Tie hazard nops to acc before VALU reads the MFMA result.
#define ACC_SYNC(acc_) asm volatile("s_nop 7\n\ts_nop 7" : "+v"(acc_))
// Pin a 4-dword value into the AGPR file.
#define PIN_A(x_) asm volatile("" : "+a"(x_))

__device__ __forceinline__ float sigf_(float x) {
  x = fminf(fmaxf(x, -30.f), 30.f);
  return 1.f / (1.f + __expf(-x));
}
__device__ __forceinline__ float tanhf_(float x) {
  x = fminf(fmaxf(x, -15.f), 15.f);
  float e = __expf(2.f * x);
  return (e - 1.f) / (e + 1.f);
}

__device__ __forceinline__ void async16(const bf16* g, bf16* l) {
  __builtin_amdgcn_global_load_lds(
      (const __attribute__((address_space(1))) u32*)g,
      (__attribute__((address_space(3))) u32*)l, 16, 0, 0);
}

// wave0 polls n flag slots (one dword each) until all nonzero.
__device__ __forceinline__ void wait_slots(int* f, int n, int tid) {
  if (tid < 64) {
    while (true) {
      int v = (tid < n) ? __hip_atomic_load(f + tid, __ATOMIC_RELAXED, SCOPE_AGENT) : 1;
      if (__all(v != 0)) break;
      __builtin_amdgcn_s_sleep(2);
    }
  }
}
__device__ __forceinline__ void post_slot(int* f) {
  __hip_atomic_store(f, 1, __ATOMIC_RELAXED, SCOPE_AGENT);
}
__device__ __forceinline__ void store_pair_at(bf16* base, size_t elem_idx, float a, float b) {
  unsigned short lo = __builtin_bit_cast(unsigned short, (bf16)a);
  unsigned short hi = __builtin_bit_cast(unsigned short, (bf16)b);
  u32 pk = (u32)lo | ((u32)hi << 16);
  __hip_atomic_store((u32*)base + (elem_idx >> 1), pk, __ATOMIC_RELAXED, SCOPE_AGENT);
}

// ---------------------------------------------------------------------------
// LSTM scan block. KREG regions of RDIM K each (mem: x+h = 2x512; enc: 1x256).
// Block owns 32 units (128 gate cols = 4 MFMA N-tiles). 4 waves K-split.
// Weights AGPR-resident. h global layout: [slot][32 m][RDIM] with 8-elem
// chunks XOR-swizzled by (m&7) so LDS copy is ds_read-friendly.
// ---------------------------------------------------------------------------
template<int KREG, int RDIM, bool PRE>
__device__ void scan_body(const bf16* __restrict__ Wrows, const float* __restrict__ biasf,
    const bf16* __restrict__ xbase, const bf16* __restrict__ hbase, bf16* __restrict__ hout,
    const float* __restrict__ cinit, const float* __restrict__ done,
    int* flag_own, int nslot_own, int* flag_x, int nslot_x, int myslot,
    int u0, int tid, char* smem)
{
  constexpr int KW = KREG * RDIM;
  constexpr int NKS = KW / 64;          // k-tiles per wave (mem 16, enc 4)
  constexpr int NI = RDIM / 16;         // load_lds instrs per region
  bf16* Abuf = (bf16*)smem;                                   // [KREG][32][RDIM]
  float* partial = (float*)(smem + KREG * 32 * RDIM * 2);     // [4][128][33]
  float* cl = partial + 4 * 128 * 33;                          // [32 m][32 u]
  const int lane = tid & 63, wv = tid >> 6;
  const int hsel = lane >> 5, ln31 = lane & 31;
  const int ks0 = wv * NKS;

  // ---- preload weights into AGPRs (time-invariant) ----
  v4i Wreg[4][NKS];
#pragma unroll
  for (int g = 0; g < 4; ++g) {
    int row = g * RDIM + u0 + ln31;
#pragma unroll
    for (int ks = 0; ks < NKS; ++ks) {
      Wreg[g][ks] = *(const v4i*)(Wrows + (size_t)row * KW + (ks0 + ks) * 16 + hsel * 8);
      PIN_A(Wreg[g][ks]);
    }
  }
  for (int i = tid; i < 1024; i += 256)
    cl[i] = cinit[(i >> 5) * RDIM + u0 + (i & 31)];

  for (int t = 0; t < 64; ++t) {
    if (t > 0) wait_slots(flag_own + (t - 1) * 16, nslot_own, tid);
    if (nslot_x > 0) wait_slots(flag_x + t * 16, nslot_x, tid);
    __syncthreads();
    // ---- stage activations: linear global -> LDS DMA ----
    for (int i = wv; i < KREG * NI; i += 4) {
      int r = i / NI, ii = i - r * NI;
      const bf16* src = (KREG == 2 && r == 0) ? xbase : hbase;
      async16(src + (size_t)t * 32 * RDIM + ii * 512 + lane * 8,
              Abuf + r * 32 * RDIM + ii * 512);
    }
    __syncthreads();

    const bool dmask = done[t * 32 + ln31] != 0.0f;
    f32x16v acc[4] = {};
#pragma unroll
    for (int ks = 0; ks < NKS; ++ks) {
      int kg = (ks0 + ks) * 16 + hsel * 8;
      int r = kg / RDIM, kk = kg - r * RDIM;
      v4i a = *(const v4i*)(Abuf + r * 32 * RDIM + ln31 * RDIM +
                            ((((kk >> 3) ^ (ln31 & 7)) << 3)));
      if (r == KREG - 1 && dmask) a = v4i{0, 0, 0, 0};
#pragma unroll
      for (int g = 0; g < 4; ++g)
        MFMA_AB(acc[g], a, Wreg[g][ks]);
    }
    ACC_SYNC(acc[0]); ACC_SYNC(acc[1]); ACC_SYNC(acc[2]); ACC_SYNC(acc[3]);
    // partial[wv][col=g*32+ln31][m]; C/D: col=lane&31, m=(reg&3)+8*(reg>>2)+4*hsel
#pragma unroll
    for (int g = 0; g < 4; ++g) {
      float* pp = partial + (wv * 128 + g * 32 + ln31) * 33 + 4 * hsel;
#pragma unroll
      for (int q = 0; q < 4; ++q)
#pragma unroll
        for (int s = 0; s < 4; ++s)
          pp[8 * q + s] = acc[g][4 * q + s];
    }
    __syncthreads();
    // pointwise: 32 m x 16 unit-pairs
    for (int p = tid; p < 512; p += 256) {
      int m = p >> 4, up = (p & 15) * 2;
      float dn = done[t * 32 + m];
      float hv[2];
#pragma unroll
      for (int j = 0; j < 2; ++j) {
        int u = up + j;
        float gg[4];
#pragma unroll
        for (int g = 0; g < 4; ++g) {
          int col = g * 32 + u;
          float s = partial[col * 33 + m] + partial[(128 + col) * 33 + m]
                  + partial[(256 + col) * 33 + m] + partial[(384 + col) * 33 + m];
          if (PRE) s += biasf[(size_t)(t * 32 + m) * (4 * RDIM) + g * RDIM + u0 + u];
          else     s += biasf[g * RDIM + u0 + u];
          gg[g] = s;
        }
        int ci = m * 32 + u;
        float cold = cl[ci] * (1.0f - dn);
        float cn = sigf_(gg[1]) * cold + sigf_(gg[0]) * tanhf_(gg[2]);
        cl[ci] = cn;
        hv[j] = sigf_(gg[3]) * tanhf_(cn);
      }
      int k = u0 + up;
      int pos = ((((k >> 3) ^ (m & 7)) << 3)) + (k & 7);
      store_pair_at(hout, ((size_t)(t + 1) * 32 + m) * RDIM + pos, hv[0], hv[1]);
    }
    __syncthreads();
    if (tid == 0) post_slot(flag_own + t * 16 + myslot);
  }
}

// ---- emb: lang_e[t] = relu(lang_h[t] @ emb_w.T + emb_b) -> hidden[:,256:288]
__device__ void emb_body(const bf16* __restrict__ Wemb, const float* __restrict__ emb_b,
    const bf16* __restrict__ h_enc, bf16* __restrict__ hidden,
    int* fle, int* flb, int t0, int tid, char* smem)
{
  bf16* Abuf = (bf16*)smem;                         // [32][256] (enc swizzle)
  float* partial = (float*)(smem + 32 * 256 * 2);   // [4][32][33]
  const int lane = tid & 63, wv = tid >> 6;
  const int hsel = lane >> 5, ln31 = lane & 31;
  const int ks0 = wv * 4;
  bf16x8 Wreg[4];
#pragma unroll
  for (int ks = 0; ks < 4; ++ks)
    Wreg[ks] = *(const bf16x8*)(Wemb + ln31 * 256 + (ks0 + ks) * 16 + hsel * 8);
  for (int t = t0; t < 64; t += 4) {
    wait_slots(fle + t * 16, 8, tid);
    __syncthreads();
    // copy (layout-preserving) h_enc slot t+1 into LDS
    {
      const uint4* s = (const uint4*)(h_enc + (size_t)(t + 1) * 32 * 256);
      for (int i = tid; i < 1024; i += 256) ((uint4*)Abuf)[i] = s[i];
    }
    __syncthreads();
    f32x16v acc = {};
#pragma unroll
    for (int ks = 0; ks < 4; ++ks) {
      int k = (ks0 + ks) * 16 + hsel * 8;
      bf16x8 a = *(const bf16x8*)(Abuf + ln31 * 256 + ((((k >> 3) ^ (ln31 & 7)) << 3)));
      acc = __builtin_amdgcn_mfma_f32_32x32x16_bf16(a, Wreg[ks], acc, 0, 0, 0);
    }
    float* pp = partial + (wv * 32 + ln31) * 33 + 4 * hsel;
#pragma unroll
    for (int q = 0; q < 4; ++q)
#pragma unroll
      for (int s = 0; s < 4; ++s)
        pp[8 * q + s] = acc[4 * q + s];
    __syncthreads();
    for (int p = tid; p < 512; p += 256) {
      int m = p >> 4, np = (p & 15) * 2;
      float v[2];
#pragma unroll
      for (int j = 0; j < 2; ++j) {
        int col = np + j;
        float s = partial[col * 33 + m] + partial[(32 + col) * 33 + m]
                + partial[(64 + col) * 33 + m] + partial[(96 + col) * 33 + m] + emb_b[col];
        v[j] = fmaxf(s, 0.f);
      }
      int k = 256 + np;
      int pos = ((((k >> 3) ^ (m & 7)) << 3)) + (k & 7);
      store_pair_at(hidden, (size_t)(t * 32 + m) * 512 + pos, v[0], v[1]);
    }
    __syncthreads();
    if (tid == 0) post_slot(flb + t * 16);
  }
}

// ---- heads: logits, log_softmax, entropy, value
__device__ void heads_body(const bf16* __restrict__ h3, const float* __restrict__ actor_w,
    const float* __restrict__ actor_b, const float* __restrict__ critic_w,
    const float* __restrict__ critic_b, const int* __restrict__ action,
    float* __restrict__ out, int* fl3, int t0, int tid, char* smem)
{
  float* hS = (float*)smem;       // [32][520]
  float* lg = hS + 32 * 520;      // [32][8]
  float* vp = lg + 256;           // [32][8]
  const int b = tid >> 3, c = tid & 7;
  for (int t = t0; t < 64; t += 8) {
    wait_slots(fl3 + t * 16, 16, tid);
    __syncthreads();
    for (int i = tid; i < 2048; i += 256) {
      int m = i >> 6, j = i & 63;   // logical chunk j
      bf16x8 v = *(const bf16x8*)(h3 + ((size_t)(t + 1) * 32 + m) * 512 +
                                  ((j ^ (m & 7)) << 3));
#pragma unroll
      for (int q = 0; q < 8; ++q) hS[m * 520 + j * 8 + q] = (float)v[q];
    }
    __syncthreads();
    float acc = actor_b[c];
    float va = 0.f;
#pragma unroll 4
    for (int k = 0; k < 512; k += 4) {
      f32x4v hv = *(const f32x4v*)(hS + b * 520 + k);
      f32x4v wv4 = *(const f32x4v*)(actor_w + c * 512 + k);
      acc += hv[0]*wv4[0] + hv[1]*wv4[1] + hv[2]*wv4[2] + hv[3]*wv4[3];
    }
    for (int k = c * 64; k < c * 64 + 64; k += 4) {
      f32x4v hv = *(const f32x4v*)(hS + b * 520 + k);
      f32x4v wv4 = *(const f32x4v*)(critic_w + k);
      va += hv[0]*wv4[0] + hv[1]*wv4[1] + hv[2]*wv4[2] + hv[3]*wv4[3];
    }
    lg[b * 8 + c] = acc;
    vp[b * 8 + c] = va;
    __syncthreads();
    if (tid < 32) {
      const float* L = lg + tid * 8;
      float mx = L[0];
#pragma unroll
      for (int i = 1; i < 8; ++i) mx = fmaxf(mx, L[i]);
      float s = 0.f;
#pragma unroll
      for (int i = 0; i < 8; ++i) s += __expf(L[i] - mx);
      float lse = mx + __logf(s);
      float ent = 0.f;
#pragma unroll
      for (int i = 0; i < 8; ++i) { float lp = L[i] - lse; ent -= __expf(lp) * lp; }
      int a = action[t * 32 + tid];
      a = a < 0 ? 0 : (a > 7 ? 7 : a);
      float val = critic_b[0];
#pragma unroll
      for (int i = 0; i < 8; ++i) val += vp[tid * 8 + i];
      float* o = out + (size_t)(t * 32 + tid) * 3;
      o[0] = L[a] - lse; o[1] = ent; o[2] = val;
    }
    __syncthreads();
  }
}

struct PipeP {
  const bf16 *Wenc, *Wm0, *Wm1, *Wm2, *Wm3, *Wemb;
  const float *pre_enc, *bc, *done, *emb_b, *enc_c0, *mem_c0;
  bf16 *hidden, *h_enc, *h_mem;
  const float *actor_w, *actor_b, *critic_w, *critic_b;
  const int *action;
  float *out;
  int *fl;
};

// flag ints: mem l: (l*64+t)*16+s (16 slots); enc: (256+t)*16+s (8); emb: (320+t)*16
// grid: 0..63 mem (16 x 4 layers), 64..71 enc, 72..75 emb, 76..83 heads
__global__ __launch_bounds__(256, 1) void pipeline_kernel(PipeP P) {
  extern __shared__ char smem[];
  const int bid = blockIdx.x, tid = threadIdx.x;
  int* fl = P.fl;
  if (bid < 64) {
    int l = bid >> 4, s = bid & 15, u0 = s * 32;
    bf16* hown = P.h_mem + (size_t)l * HM_ELEMS;
    const bf16* W = (l == 0) ? P.Wm0 : (l == 1) ? P.Wm1 : (l == 2) ? P.Wm2 : P.Wm3;
    const bf16* xb = (l == 0) ? P.hidden : P.h_mem + (size_t)(l - 1) * HM_ELEMS + 32 * 512;
    int* fown = fl + l * 1024;
    int* fx = (l == 0) ? fl + 320 * 16 : fl + (l - 1) * 1024;
    int nx = (l == 0) ? 1 : 16;
    scan_body<2, 512, false>(W, P.bc + l * 2048, xb, hown, hown,
        P.mem_c0 + l * 32 * 512, P.done, fown, 16, fx, nx, s, u0, tid, smem);
  } else if (bid < 72) {
    int s = bid - 64, u0 = s * 32;
    scan_body<1, 256, true>(P.Wenc, P.pre_enc, nullptr, P.h_enc, P.h_enc,
        P.enc_c0, P.done, fl + 256 * 16, 8, nullptr, 0, s, u0, tid, smem);
  } else if (bid < 76) {
    emb_body(P.Wemb, P.emb_b, P.h_enc, P.hidden, fl + 256 * 16, fl + 320 * 16,
             bid - 72, tid, smem);
  } else {
    heads_body(P.h_mem + 3ull * HM_ELEMS, P.actor_w, P.actor_b, P.critic_w, P.critic_b,
        P.action, P.out, fl + 3 * 1024, bid - 76, tid, smem);
  }
}

// ---------------------------------------------------------------------------
// prep: vectorized (8 elems/thread) weight conversions / swizzled h0 slots
// ---------------------------------------------------------------------------
__device__ __forceinline__ void cvt_store8(bf16* dst, const float* src) {
  f32x4v a = *(const f32x4v*)src, b = *(const f32x4v*)(src + 4);
  bf16x8 o;
#pragma unroll
  for (int j = 0; j < 4; ++j) { o[j] = (bf16)a[j]; o[4 + j] = (bf16)b[j]; }
  *(bf16x8*)dst = o;
}

__global__ void prep_kernel(
    const float* __restrict__ enc_Whh, const float* __restrict__ mem_Wih0,
    const float* __restrict__ mem_WihR, const float* __restrict__ mem_Whh,
    const float* __restrict__ emb_w, const float* __restrict__ mem_bih,
    const float* __restrict__ mem_bhh, const float* __restrict__ enc_h0,
    const float* __restrict__ mem_h0, const float* __restrict__ fc_w,
    const float* __restrict__ conv1_w,
    bf16* __restrict__ Wenc, bf16* __restrict__ Wm0, bf16* __restrict__ Wm123,
    bf16* __restrict__ Wemb, float* __restrict__ bc,
    bf16* __restrict__ h_enc, bf16* __restrict__ h_mem, bf16* __restrict__ fcw_bf,
    bf16* __restrict__ w1bf)
{
  int v = blockIdx.x * 256 + threadIdx.x;   // 8-elem vector index
  if (v < 32768) { cvt_store8(Wenc + v * 8, enc_Whh + v * 8); return; }
  v -= 32768;
  if (v < 262144) {   // Wm0 [2048 cols][1024 k]: 288 Wih0 | 224 zero | 512 Whh
    int col = v >> 7, c = v & 127;
    bf16x8 o = {};
    if (c < 36) {
      const float* s = mem_Wih0 + col * 288 + c * 8;
#pragma unroll
      for (int j = 0; j < 8; ++j) o[j] = (bf16)s[j];
    } else if (c >= 64) {
      const float* s = mem_Whh + col * 512 + (c - 64) * 8;
#pragma unroll
      for (int j = 0; j < 8; ++j) o[j] = (bf16)s[j];
    }
    *(bf16x8*)(Wm0 + (size_t)v * 8) = o;
    return;
  }
  v -= 262144;
  if (v < 786432) {   // Wm1..3 [l][2048 cols][1024 k]: 512 WihR | 512 Whh
    int l = v >> 18, r = v & 262143, col = r >> 7, c = r & 127;
    const float* s = (c < 64) ? mem_WihR + ((size_t)(l * 2048 + col)) * 512 + c * 8
                              : mem_Whh + ((size_t)((l + 1) * 2048 + col)) * 512 + (c - 64) * 8;
    cvt_store8(Wm123 + (size_t)v * 8, s);
    return;
  }
  v -= 786432;
  if (v < 1024) { cvt_store8(Wemb + v * 8, emb_w + v * 8); return; }
  v -= 1024;
  if (v < 1024) {
#pragma unroll
    for (int j = 0; j < 8; ++j) bc[v * 8 + j] = mem_bih[v * 8 + j] + mem_bhh[v * 8 + j];
    return;
  }
  v -= 1024;
  if (v < 1024) {     // h_enc slot 0 (swizzled)
    int m = v >> 5, c = v & 31;
    bf16x8 o;
    const float* s = enc_h0 + m * 256 + c * 8;
#pragma unroll
    for (int j = 0; j < 8; ++j) o[j] = (bf16)s[j];
    *(bf16x8*)(h_enc + m * 256 + ((c ^ (m & 7)) << 3)) = o;
    return;
  }
  v -= 1024;
  if (v < 8192) {     // h_mem slot 0 per layer (swizzled)
    int l = v >> 11, r = v & 2047, m = r >> 6, c = r & 63;
    bf16x8 o;
    const float* s = mem_h0 + ((size_t)(l * 32 + m)) * 512 + c * 8;
#pragma unroll
    for (int j = 0; j < 8; ++j) o[j] = (bf16)s[j];
    *(bf16x8*)(h_mem + (size_t)l * HM_ELEMS + m * 512 + ((c ^ (m & 7)) << 3)) = o;
    return;
  }
  v -= 8192;
  if (v < 50176) { cvt_store8(fcw_bf + (size_t)v * 8, fc_w + (size_t)v * 8); return; }
  v -= 50176;
  if (v < 512) {      // conv1 weights [16 oc][256 k] zero-padded
    int oc = v >> 5, c = v & 31;
    bf16x8 o = {};
#pragma unroll
    for (int j = 0; j < 8; ++j) {
      int k = c * 8 + j;
      if (k < 243) o[j] = (bf16)conv1_w[oc * 243 + k];
    }
    *(bf16x8*)(w1bf + v * 8) = o;
    return;
  }
}

__global__ void pre_enc_kernel(const float* __restrict__ lang, const float* __restrict__ Wih,
    const float* __restrict__ bih, const float* __restrict__ bhh, float* __restrict__ pre)
{
  int idx = blockIdx.x * 256 + threadIdx.x;
  if (idx >= 64 * 32 * 1024) return;
  int col = idx & 1023, bm = idx >> 10;
  float acc = bih[col] + bhh[col];
  const float* lp = lang + bm * 14;
  const float* wp = Wih + col * 14;
#pragma unroll
  for (int k = 0; k < 14; ++k) acc += lp[k] * wp[k];
  pre[idx] = acc;
}

// ---------------------------------------------------------------------------
// conv1 as MFMA GEMM (stride 9 == kernel 9 -> disjoint patches)
// ---------------------------------------------------------------------------
__global__ __launch_bounds__(256) void conv1_mfma(const float* __restrict__ img,
    const bf16* __restrict__ w1bf, const float* __restrict__ bias, float* __restrict__ out) {
  __shared__ bf16 sP[128 * 256];
  const int n = blockIdx.x, tid = threadIdx.x;
  const int lane = tid & 63, wv = tid >> 6;
  for (int i = tid; i < 4096; i += 256) ((uint4*)sP)[i] = uint4{0u, 0u, 0u, 0u};
  __syncthreads();
  const float* ib = img + (size_t)n * 29403;
  for (int e = tid; e < 29403; e += 256) {
    int c = e / 9801, r = e - c * 9801;
    int h = r / 99, w = r - h * 99;
    int oh = h / 9, kh = h - oh * 9;
    int ow = w / 9, kw = w - ow * 9;
    int p = oh * 11 + ow;
    int k = c * 81 + kh * 9 + kw;
    sP[p * 256 + (k ^ ((p & 15) * 8))] = (bf16)ib[e];
  }
  __syncthreads();
  const int oc = lane & 15, kg = lane >> 4;
  bf16x8 bfr[8];
#pragma unroll
  for (int ks = 0; ks < 8; ++ks)
    bfr[ks] = *(const bf16x8*)(w1bf + oc * 256 + ks * 32 + kg * 8);
  const float bv = bias[oc];
#pragma unroll
  for (int mt2 = 0; mt2 < 2; ++mt2) {
    int mt = wv * 2 + mt2;
    int p = mt * 16 + (lane & 15);
    f32x4v acc = {};
#pragma unroll
    for (int ks = 0; ks < 8; ++ks) {
      int k0 = ks * 32 + kg * 8;
      bf16x8 a = *(const bf16x8*)(sP + p * 256 + (k0 ^ ((p & 15) * 8)));
      acc = __builtin_amdgcn_mfma_f32_16x16x32_bf16(a, bfr[ks], acc, 0, 0, 0);
    }
#pragma unroll
    for (int s = 0; s < 4; ++s) {
      int pm = mt * 16 + (lane >> 4) * 4 + s;
      if (pm < 121)
        out[((size_t)n * 16 + oc) * 121 + pm] = fmaxf(acc[s] + bv, 0.f);
    }
  }
}

// ---------------------------------------------------------------------------
// conv2/conv3 register-tiled: thread owns (oc, oh) row; weights+input in regs
// ---------------------------------------------------------------------------
__global__ void conv2_kernel(const float* __restrict__ in, const float* __restrict__ w,
                             const float* __restrict__ bias, float* __restrict__ out) {
  int n = blockIdx.x;
  __shared__ float sIn[16 * 121];
  __shared__ float sW[32 * 144];
  int tid = threadIdx.x;
  for (int i = tid; i < 4608; i += 256) sW[i] = w[i];
  for (int i = tid; i < 1936; i += 256) sIn[i] = in[(size_t)n * 1936 + i];
  __syncthreads();
  for (int task = tid; task < 288; task += 256) {
    int oc = task & 31, oh = task >> 5;
    float acc[9];
    float bv = bias[oc];
#pragma unroll
    for (int ow = 0; ow < 9; ++ow) acc[ow] = bv;
    for (int c = 0; c < 16; ++c) {
      const float* wr = sW + oc * 144 + c * 9;
      float wq[9];
#pragma unroll
      for (int q = 0; q < 9; ++q) wq[q] = wr[q];
#pragma unroll
      for (int kh = 0; kh < 3; ++kh) {
        const float* ir = sIn + c * 121 + (oh + kh) * 11;
        float iv[11];
#pragma unroll
        for (int q = 0; q < 11; ++q) iv[q] = ir[q];
#pragma unroll
        for (int ow = 0; ow < 9; ++ow)
          acc[ow] += wq[kh*3]*iv[ow] + wq[kh*3+1]*iv[ow+1] + wq[kh*3+2]*iv[ow+2];
      }
    }
#pragma unroll
    for (int ow = 0; ow < 9; ++ow)
      out[(size_t)n * 2592 + oc * 81 + oh * 9 + ow] = fmaxf(acc[ow], 0.f);
  }
}

__global__ void conv3_kernel(const float* __restrict__ in, const float* __restrict__ w,
                             const float* __restrict__ bias, float* __restrict__ out) {
  int n = blockIdx.x;
  __shared__ float sIn[32 * 81];
  __shared__ float sW[32 * 288];
  int tid = threadIdx.x;
  for (int i = tid; i < 9216; i += 256) sW[i] = w[i];
  for (int i = tid; i < 2592; i += 256) sIn[i] = in[(size_t)n * 2592 + i];
  __syncthreads();
  for (int task = tid; task < 224; task += 256) {
    int oc = task & 31, oh = task >> 5;
    float acc[7];
    float bv = bias[oc];
#pragma unroll
    for (int ow = 0; ow < 7; ++ow) acc[ow] = bv;
    for (int c = 0; c < 32; ++c) {
      const float* wr = sW + oc * 288 + c * 9;
      float wq[9];
#pragma unroll
      for (int q = 0; q < 9; ++q) wq[q] = wr[q];
#pragma unroll
      for (int kh = 0; kh < 3; ++kh) {
        const float* ir = sIn + c * 81 + (oh + kh) * 9;
        float iv[9];
#pragma unroll
        for (int q = 0; q < 9; ++q) iv[q] = ir[q];
#pragma unroll
        for (int ow = 0; ow < 7; ++ow)
          acc[ow] += wq[kh*3]*iv[ow] + wq[kh*3+1]*iv[ow+1] + wq[kh*3+2]*iv[ow+2];
      }
    }
#pragma unroll
    for (int ow = 0; ow < 7; ++ow)
      out[(size_t)n * 1568 + oc * 49 + oh * 7 + ow] = fmaxf(acc[ow], 0.f);
  }
}

// ---- fc: (2048x1568)@(1568x256) bf16 MFMA -> relu -> hidden[:, :256] (swizzled)
__global__ __launch_bounds__(256) void fc_kernel(const float* __restrict__ a3,
    const bf16* __restrict__ wbf, const float* __restrict__ fc_b, bf16* __restrict__ hidden) {
  __shared__ bf16 sA[64 * 72];
  __shared__ bf16 sB[64 * 72];
  int bid = blockIdx.x, tid = threadIdx.x;
  int rg = bid >> 2, cg = bid & 3;
  int r0 = rg * 64, c0 = cg * 64;
  int lane = tid & 63, wv = tid >> 6, hsel = lane >> 5, ln31 = lane & 31;
  int wm = wv >> 1, wn = wv & 1;
  f32x16v acc = {};
  for (int kb = 0; kb < 1568; kb += 64) {
    __syncthreads();
    for (int i = tid; i < 512; i += 256) {
      int r = i >> 3, kk = (i & 7) * 8;
      int k = kb + kk;
      bf16x8 va = {}, vb = {};
      if (k < 1568) {
        const float* p = a3 + (size_t)(r0 + r) * 1568 + k;
#pragma unroll
        for (int j = 0; j < 8; ++j) va[j] = (bf16)p[j];
        vb = *(const bf16x8*)(wbf + (size_t)(c0 + r) * 1568 + k);
      }
      *(bf16x8*)(sA + r * 72 + kk) = va;
      *(bf16x8*)(sB + r * 72 + kk) = vb;
    }
    __syncthreads();
#pragma unroll
    for (int ks = 0; ks < 4; ++ks) {
      int k = ks * 16 + hsel * 8;
      bf16x8 a = *(const bf16x8*)(sA + (wm * 32 + ln31) * 72 + k);
      bf16x8 b = *(const bf16x8*)(sB + (wn * 32 + ln31) * 72 + k);
      acc = __builtin_amdgcn_mfma_f32_32x32x16_bf16(a, b, acc, 0, 0, 0);
    }
  }
  int cc = c0 + wn * 32 + ln31;
  float bv = fc_b[cc];
#pragma unroll
  for (int q = 0; q < 4; ++q)
#pragma unroll
    for (int s = 0; s < 4; ++s) {
      int m = 8 * q + 4 * hsel + s;
      int row = r0 + wm * 32 + m;
      int b = row & 31;
      int pos = ((((cc >> 3) ^ (b & 7)) << 3)) + (cc & 7);
      hidden[(size_t)row * 512 + pos] = (bf16)fmaxf(acc[4 * q + s] + bv, 0.f);
    }
}

// ---------------------------------------------------------------------------
extern "C" void kernel_launch(void* const* d_in, const int* in_sizes, int n_in,
                              void* d_out, int out_size, void* d_ws, size_t ws_size,
                              hipStream_t stream)
{
  const float* img      = (const float*)d_in[0];
  const float* lang     = (const float*)d_in[1];
  const float* done     = (const float*)d_in[2];
  const int*   action   = (const int*)d_in[3];
  const float* enc_h0   = (const float*)d_in[4];
  const float* enc_c0   = (const float*)d_in[5];
  const float* mem_h0   = (const float*)d_in[6];
  const float* mem_c0   = (const float*)d_in[7];
  const float* conv1_w  = (const float*)d_in[8];
  const float* conv1_b  = (const float*)d_in[9];
  const float* conv2_w  = (const float*)d_in[10];
  const float* conv2_b  = (const float*)d_in[11];
  const float* conv3_w  = (const float*)d_in[12];
  const float* conv3_b  = (const float*)d_in[13];
  const float* fc_w     = (const float*)d_in[14];
  const float* fc_b     = (const float*)d_in[15];
  const float* enc_Wih  = (const float*)d_in[16];
  const float* enc_Whh  = (const float*)d_in[17];
  const float* enc_bih  = (const float*)d_in[18];
  const float* enc_bhh  = (const float*)d_in[19];
  const float* emb_w    = (const float*)d_in[20];
  const float* emb_b    = (const float*)d_in[21];
  const float* mem_Wih0 = (const float*)d_in[22];
  const float* mem_WihR = (const float*)d_in[23];
  const float* mem_Whh  = (const float*)d_in[24];
  const float* mem_bih  = (const float*)d_in[25];
  const float* mem_bhh  = (const float*)d_in[26];
  const float* actor_w  = (const float*)d_in[27];
  const float* actor_b  = (const float*)d_in[28];
  const float* critic_w = (const float*)d_in[29];
  const float* critic_b = (const float*)d_in[30];
  float* out = (float*)d_out;
  (void)in_sizes; (void)n_in; (void)out_size; (void)ws_size;

  char* wp = (char*)d_ws;
  auto alloc = [&](size_t b) { char* p = wp; wp += (b + 255) & ~(size_t)255; return p; };
  float* A1     = (float*)alloc(2048ull * 16 * 121 * 4);
  float* A2     = (float*)alloc(2048ull * 32 * 81 * 4);
  bf16*  hidden = (bf16*) alloc(2048ull * 512 * 2);          // [TB][512] swizzled, zero-pad
  float* preenc = (float*)alloc(64ull * 32 * 1024 * 4);
  bf16*  Wenc   = (bf16*) alloc(1024ull * 256 * 2);
  bf16*  Wm0    = (bf16*) alloc(2048ull * 1024 * 2);
  bf16*  Wm123  = (bf16*) alloc(3ull * 2048 * 1024 * 2);
  bf16*  Wemb   = (bf16*) alloc(32ull * 256 * 2);
  float* bc     = (float*)alloc(4ull * 2048 * 4);
  bf16*  h_enc  = (bf16*) alloc(65ull * 32 * 256 * 2);
  bf16*  h_mem  = (bf16*) alloc(4ull * HM_ELEMS * 2);
  bf16*  fcwbf  = (bf16*) alloc(256ull * 1568 * 2);
  bf16*  w1bf   = (bf16*) alloc(16ull * 256 * 2);
  int*   fl     = (int*)  alloc(24576);
  float* A3     = A1;

  hipMemsetAsync(fl, 0, 24576, stream);
  hipMemsetAsync(hidden, 0, 2048ull * 512 * 2, stream);
  prep_kernel<<<4466, 256, 0, stream>>>(enc_Whh, mem_Wih0, mem_WihR, mem_Whh, emb_w,
      mem_bih, mem_bhh, enc_h0, mem_h0, fc_w, conv1_w,
      Wenc, Wm0, Wm123, Wemb, bc, h_enc, h_mem, fcwbf, w1bf);
  pre_enc_kernel<<<8192, 256, 0, stream>>>(lang, enc_Wih, enc_bih, enc_bhh, preenc);
  conv1_mfma<<<2048, 256, 0, stream>>>(img, w1bf, conv1_b, A1);
  conv2_kernel<<<2048, 256, 0, stream>>>(A1, conv2_w, conv2_b, A2);
  conv3_kernel<<<2048, 256, 0, stream>>>(A2, conv3_w, conv3_b, A3);
  fc_kernel<<<128, 256, 0, stream>>>(A3, fcwbf, fc_b, hidden);

  PipeP P;
  P.Wenc = Wenc; P.Wm0 = Wm0; P.Wm1 = Wm123;
  P.Wm2 = Wm123 + 2048ull * 1024; P.Wm3 = Wm123 + 2ull * 2048 * 1024;
  P.Wemb = Wemb; P.pre_enc = preenc; P.bc = bc; P.done = done; P.emb_b = emb_b;
  P.enc_c0 = enc_c0; P.mem_c0 = mem_c0; P.hidden = hidden; P.h_enc = h_enc; P.h_mem = h_mem;
  P.actor_w = actor_w; P.actor_b = actor_b; P.critic_w = critic_w; P.critic_b = critic_b;
  P.action = action; P.out = out; P.fl = fl;

  (void)hipFuncSetAttribute((const void*)pipeline_kernel,
      hipFuncAttributeMaxDynamicSharedMemorySize, 137216);
  pipeline_kernel<<<84, 256, 137216, stream>>>(P);
}